// Round 10
// baseline (201.446 us; speedup 1.0000x reference)
//
#include <hip/hip_runtime.h>
#include <math.h>

#define TT  1024
#define BB  2048
#define FF  11
#define PP  256
#define NG  100
#define NCH 32           // chunks over T
#define LCH (TT / NCH)   // 32 steps per chunk
#define JJ  4            // phaseC unroll / prefetch depth

typedef float f32x2 __attribute__((ext_vector_type(2)));

__device__ __forceinline__ float nz(float v) { return (v != v) ? 0.f : v; }

// Branch-free erf, Abramowitz-Stegun 7.1.26, |err| <= 1.5e-7 (abs).
__device__ __forceinline__ float erf_fast(float x) {
    float ax = fabsf(x);
    float t  = __builtin_amdgcn_rcpf(fmaf(0.3275911f, ax, 1.f));
    float y  = fmaf(fmaf(fmaf(fmaf(1.061405429f, t, -1.453152027f), t,
                              1.421413741f), t, -0.284496736f), t, 0.254829592f);
    y *= t;
    float r = fmaf(-y, __expf(-ax * ax), 1.f);
    return copysignf(r, x);
}

// q coefficients for one (t,b) record. Returns (q0, q1, B0=beta*pi1n, B1=beta*pi0n).
__device__ __forceinline__ float4 q_from_rec(
    float a0, float a1, float r0, float r1, float cdc, float cdn,
    float beta, float inv_s)
{
    float u = 0.5f * (1.f + erf_fast((0.0f  - cdc) * inv_s));
    float v = 0.5f * (1.f + erf_fast((-0.1f - cdc) * inv_s));
    float w = 0.5f * (1.f + erf_fast((0.1f  - cdc) * inv_s));
    float inv = 1.f / fmaxf(w - v, 1e-10f);
    float pi0 = fminf(fmaxf((u - v) * inv, 0.f), 1.f);
    float pi1 = fminf(fmaxf((w - u) * inv, 0.f), 1.f);

    u = 0.5f * (1.f + erf_fast((0.0f  - cdn) * inv_s));
    v = 0.5f * (1.f + erf_fast((-0.1f - cdn) * inv_s));
    w = 0.5f * (1.f + erf_fast((0.1f  - cdn) * inv_s));
    inv = 1.f / fmaxf(w - v, 1e-10f);
    float pi0n = fminf(fmaxf((u - v) * inv, 0.f), 1.f);
    float pi1n = fminf(fmaxf((w - u) * inv, 0.f), 1.f);

    float rs = r0 * a0 + r1 * a1;
    float r  = (a0 >= a1) ? rs : 1.f - rs;      // argmax tie -> index 0
    float q0 = pi1 * r + pi0 * (1.f - r);
    float q1 = (2.f * r - 1.f) * (pi0 - pi1);
    if (!((a0 + a1) > 0.f)) { q0 = 1.f; q1 = 0.f; }
    return make_float4(q0, q1, beta * pi1n, beta * pi0n);
}

// be' = max(be*u, 1e-30) composes over a chunk as be_out = max(be_in*U, C):
// U = prod(u), C = max-scan of floor. Exact semantics, scan-able over T.

// ---------------- Phase Aq: fused coeff-compute + per-chunk (U,C) ------------
// Lane mapping: g = lane&7 (batch within octet), sl = lane>>3 (step/slot).
// Consecutive lanes -> consecutive b: record loads stride 44 B (coalesced-ish),
// QC stores 128 B contiguous per sl-group. Per 8-step block, lane (sl,g)
// computes record (t0+tt+sl, b_g); group consumes q via __shfl(.., 8j+g).
// Lane owns 7 slot-pairs {sl+16k, sl+16k+8}; grid points >=100 are hard zeros.
__global__ __launch_bounds__(256) void phaseAq_kernel(
    const float* __restrict__ x, const float* __restrict__ beta_raw,
    const float* __restrict__ sigma_raw, float4* __restrict__ QC,
    float2* __restrict__ UC)
{
    const int lane = threadIdx.x & 63;
    const int wib  = threadIdx.x >> 6;
    const int W    = blockIdx.x * 4 + wib;       // 0..8191
    const int wg   = W & 255;                    // b-octet
    const int c    = W >> 8;                     // chunk 0..31
    const int g    = lane & 7;
    const int sl   = lane >> 3;
    const int b    = wg * 8 + g;
    const int t0   = c * LCH;

    // per-b participant params (8 sl-lanes of a b redundant; coalesced reads)
    int pid = (int)nz(x[(size_t)b * FF + 10]);
    pid = pid < 0 ? 0 : (pid > PP - 1 ? PP - 1 : pid);
    float br = beta_raw[pid];
    float sr = sigma_raw[pid];
    float sp   = fmaxf(br, 0.f) + log1pf(__expf(-fabsf(br)));
    float beta = fminf(fmaxf(sp + 1.f, 1.f), 25.f);
    float sig  = fminf(fmaxf(__builtin_amdgcn_rcpf(1.f + __expf(-sr)) * 0.09f + 0.01f,
                             0.01f), 0.1f);
    float inv_s = 1.f / (sig * 1.41421356237309505f);

    f32x2 p[7];
    #pragma unroll
    for (int k = 0; k < 7; ++k)
        p[k] = (f32x2){ (float)(sl + 16 * k)     * (1.f / 99.f),
                        (float)(sl + 16 * k + 8) * (1.f / 99.f) };
    const f32x2 clA = { 1e-30f, 1e-30f };
    const f32x2 cl6 = { (sl < 4) ? 1e-30f : 0.f, 0.f };   // pair 6: i=96..111

    f32x2 U[7], C[7];
    #pragma unroll
    for (int k = 0; k < 7; ++k) { U[k] = (f32x2){1.f, 1.f}; C[k] = (f32x2){0.f, 0.f}; }

    // first record for this lane: t = t0 + sl
    const float* rp = x + ((size_t)(t0 + sl) * BB + b) * FF;
    float4 qc;
    {
        float a0 = nz(rp[0]), a1 = nz(rp[1]), r0 = nz(rp[2]),
              r1 = nz(rp[3]), dc = nz(rp[4]), dn = nz(rp[5]);
        qc = q_from_rec(a0, a1, r0, r1, dc, dn, beta, inv_s);
        QC[(size_t)(t0 + sl) * BB + b] = qc;
    }

    for (int tt = 0; tt < LCH; tt += 8) {
        const bool have = (tt + 8) < LCH;
        float na0, na1, nr0, nr1, ndc, ndn;
        if (have) {   // uniform branch; prefetch next block's record
            const float* np = x + ((size_t)(t0 + tt + 8 + sl) * BB + b) * FF;
            na0 = nz(np[0]); na1 = nz(np[1]); nr0 = nz(np[2]);
            nr1 = nz(np[3]); ndc = nz(np[4]); ndn = nz(np[5]);
        }
        // broadcast current block's q to the 8 lanes owning this b
        float q0b[8], q1b[8];
        #pragma unroll
        for (int j = 0; j < 8; ++j) {
            q0b[j] = __shfl(qc.x, 8 * j + g);
            q1b[j] = __shfl(qc.y, 8 * j + g);
        }
        #pragma unroll
        for (int j = 0; j < 8; ++j) {
            f32x2 qx = { q0b[j], q0b[j] }, qy = { q1b[j], q1b[j] };
            #pragma unroll
            for (int k = 0; k < 7; ++k) {
                f32x2 u = qy * p[k] + qx;            // v_pk_fma_f32
                U[k] *= u;
                C[k] = __builtin_elementwise_max(C[k] * u, (k == 6) ? cl6 : clA);
            }
        }
        if (have) {   // compute + store next block's record
            qc = q_from_rec(na0, na1, nr0, nr1, ndc, ndn, beta, inv_s);
            QC[(size_t)(t0 + tt + 8 + sl) * BB + b] = qc;
        }
    }

    // UC layout [c][i][b]: consecutive lanes (b) -> coalesced float2 stores
    float2* dst = UC + (size_t)c * (NG * BB) + b;
    #pragma unroll
    for (int k = 0; k < 6; ++k) {
        dst[(size_t)(sl + 16 * k) * BB]     = make_float2(U[k].x, C[k].x);
        dst[(size_t)(sl + 16 * k + 8) * BB] = make_float2(U[k].y, C[k].y);
    }
    if (sl < 4) dst[(size_t)(sl + 96) * BB] = make_float2(U[6].x, C[6].x);
}

// ---------------- Phase B: 32-step scan over chunks per (i,b) ----------------
// flat = i*BB + b (layout [c][i][b]); elementwise over flat, coalesced.
__global__ __launch_bounds__(256) void phaseB_kernel(
    const float2* __restrict__ UC, float* __restrict__ BE)
{
    const int flat = blockIdx.x * 256 + threadIdx.x;
    float be = 1.f;
    #pragma unroll
    for (int c = 0; c < NCH; ++c) {
        BE[(size_t)c * (BB * NG) + flat] = be;
        float2 uc = UC[(size_t)c * (BB * NG) + flat];
        be = fmaxf(be * uc.x, uc.y);
    }
}

// ---------------- Phase C: parallel chunk re-walk, logits + carry ------------
// 8 lanes per b (sl = lane&7 -> contiguous groups, DPP-friendly), 8 b per wave.
__global__ __launch_bounds__(256) void phaseC_kernel(
    const float4* __restrict__ QC, const float* __restrict__ BE,
    float* __restrict__ out)
{
    const int lane = threadIdx.x & 63;
    const int wib  = threadIdx.x >> 6;
    const int W    = blockIdx.x * 4 + wib;       // 0..8191
    const int wg   = W & 255;                    // b-octet
    const int c    = W >> 8;                     // chunk 0..31
    const int sl   = lane & 7;
    const int g    = lane >> 3;
    const int b    = wg * 8 + g;
    const int t0   = c * LCH;

    f32x2 p[7];
    #pragma unroll
    for (int k = 0; k < 7; ++k)
        p[k] = (f32x2){ (float)(sl + 16 * k)     * (1.f / 99.f),
                        (float)(sl + 16 * k + 8) * (1.f / 99.f) };
    const f32x2 clA = { 1e-30f, 1e-30f };
    const f32x2 cl6 = { (sl < 4) ? 1e-30f : 0.f, 0.f };   // pair 6: i=96..111

    // chunk-entry beliefs from BE[c][i][b] (7 scattered loads, once per wave)
    const float* ebase = BE + (size_t)c * (BB * NG) + b;
    f32x2 be[7];
    #pragma unroll
    for (int k = 0; k < 6; ++k)
        be[k] = (f32x2){ ebase[(size_t)(sl + 16 * k) * BB],
                         ebase[(size_t)(sl + 16 * k + 8) * BB] };
    be[6] = (f32x2){ (sl < 4) ? ebase[(size_t)(sl + 96) * BB] : 0.f, 0.f };

    const char* QCb = (const char*)QC;
    char* outb = (char*)out;
    unsigned off  = ((unsigned)t0 * BB + (unsigned)b) * 16u;          // QC bytes
    unsigned soff = ((unsigned)t0 * (2 * BB) + 2 * (unsigned)b) * 4u; // out bytes

    float4 pre[JJ];
    #pragma unroll
    for (int j = 0; j < JJ; ++j)
        pre[j] = *(const float4*)(QCb + (off + (unsigned)j * (BB * 16u)));
    off += JJ * (BB * 16u);

    for (int tt = 0; tt < LCH; tt += JJ) {
        float S[JJ], Sp[JJ], Zv[JJ], Wv[JJ];
        #pragma unroll
        for (int j = 0; j < JJ; ++j) {
            float4 q = pre[j];
            // overrun prefetch (last iter, c=31) lands in UC region: never used
            pre[j] = *(const float4*)(QCb + (off + (unsigned)j * (BB * 16u)));
            f32x2 qx = { q.x, q.x }, qy = { q.y, q.y };
            #pragma unroll
            for (int k = 0; k < 7; ++k) {
                f32x2 u = qy * p[k] + qx;
                be[k] = __builtin_elementwise_max(be[k] * u,
                                                  (k == 6) ? cl6 : clA);
            }
            f32x2 sA = ((be[0] + be[1]) + (be[2] + be[3]))
                     + ((be[4] + be[5]) + be[6]);
            S[j] = sA.x + sA.y;
            f32x2 a1 = be[0] * p[0], a2 = be[1] * p[1];
            a1 = be[2] * p[2] + a1;  a2 = be[3] * p[3] + a2;
            a1 = be[4] * p[4] + a1;  a2 = be[5] * p[5] + a2;
            a1 = be[6] * p[6] + a1;
            f32x2 aa = a1 + a2;
            Sp[j] = aa.x + aa.y;
            Zv[j] = q.z;
            Wv[j] = q.w;
        }
        off += JJ * (BB * 16u);
        #pragma unroll
        for (int j = 0; j < JJ; ++j) {
            // 8-lane butterfly sum (pure VALU DPP)
            float st = S[j], sr = Sp[j];
            {
                int t;
                t = __builtin_amdgcn_update_dpp(0, __float_as_int(st), 0xB1, 0xF, 0xF, true);
                st += __int_as_float(t);
                t = __builtin_amdgcn_update_dpp(0, __float_as_int(sr), 0xB1, 0xF, 0xF, true);
                sr += __int_as_float(t);
                t = __builtin_amdgcn_update_dpp(0, __float_as_int(st), 0x4E, 0xF, 0xF, true);
                st += __int_as_float(t);
                t = __builtin_amdgcn_update_dpp(0, __float_as_int(sr), 0x4E, 0xF, 0xF, true);
                sr += __int_as_float(t);
                t = __builtin_amdgcn_update_dpp(0, __float_as_int(st), 0x141, 0xF, 0xF, true);
                st += __int_as_float(t);
                t = __builtin_amdgcn_update_dpp(0, __float_as_int(sr), 0x141, 0xF, 0xF, true);
                sr += __int_as_float(t);
            }
            float E  = sr * __builtin_amdgcn_rcpf(st);
            float A  = Wv[j] - Zv[j];
            float l0 = fmaf(A, E, Zv[j]);
            float l1 = fmaf(-A, E, Wv[j]);
            if (sl == 0)   // 8 lanes store 8B each; octet is 64B contiguous
                *(float2*)(outb + (soff + (unsigned)j * (2 * BB * 4u))) =
                    make_float2(l0, l1);
        }
        soff += JJ * (2 * BB * 4u);
    }

    if (c == NCH - 1) {   // final belief carry: out[T*B*2 + b*100 + i]
        float* bel = out + (size_t)TT * BB * 2 + (size_t)b * NG;
        #pragma unroll
        for (int k = 0; k < 6; ++k) {
            bel[sl + 16 * k]     = be[k].x;
            bel[sl + 16 * k + 8] = be[k].y;
        }
        if (sl < 4) bel[sl + 96] = be[6].x;
    }
}

extern "C" void kernel_launch(void* const* d_in, const int* in_sizes, int n_in,
                              void* d_out, int out_size, void* d_ws, size_t ws_size,
                              hipStream_t stream)
{
    const float* x         = (const float*)d_in[0];
    const float* beta_raw  = (const float*)d_in[1];
    const float* sigma_raw = (const float*)d_in[2];
    float* out = (float*)d_out;

    // workspace: QC (32 MiB) | UC (52.4 MB) | BE (26.2 MB)  ~= 110 MB
    char* ws = (char*)d_ws;
    float4* QC = (float4*)ws;
    float2* UC = (float2*)(ws + (size_t)TT * BB * 16);
    float*  BE = (float*) (ws + (size_t)TT * BB * 16 + (size_t)NCH * BB * NG * 8);

    phaseAq_kernel<<<(BB / 8) * NCH / 4, 256, 0, stream>>>(x, beta_raw, sigma_raw, QC, UC);
    phaseB_kernel<<<(BB * NG) / 256, 256, 0, stream>>>(UC, BE);
    phaseC_kernel<<<(BB / 8) * NCH / 4, 256, 0, stream>>>(QC, BE, out);
}

// Round 11
// 196.125 us; speedup vs baseline: 1.0271x; 1.0271x over previous
//
#include <hip/hip_runtime.h>
#include <math.h>

#define TT  1024
#define BB  2048
#define FF  11
#define PP  256
#define NG  100
#define NCH 32           // chunks over T
#define LCH (TT / NCH)   // 32 steps per chunk
#define JJ  4            // phaseC unroll / prefetch depth

typedef float f32x2 __attribute__((ext_vector_type(2)));

__device__ __forceinline__ float nz(float v) { return (v != v) ? 0.f : v; }

// Branch-free erf, Abramowitz-Stegun 7.1.26, |err| <= 1.5e-7 (abs).
__device__ __forceinline__ float erf_fast(float x) {
    float ax = fabsf(x);
    float t  = __builtin_amdgcn_rcpf(fmaf(0.3275911f, ax, 1.f));
    float y  = fmaf(fmaf(fmaf(fmaf(1.061405429f, t, -1.453152027f), t,
                              1.421413741f), t, -0.284496736f), t, 0.254829592f);
    y *= t;
    float r = fmaf(-y, __expf(-ax * ax), 1.f);
    return copysignf(r, x);
}

// q coefficients for one (t,b) record. Returns (q0, q1, B0=beta*pi1n, B1=beta*pi0n).
__device__ __forceinline__ float4 q_from_rec(
    float a0, float a1, float r0, float r1, float cdc, float cdn,
    float beta, float inv_s)
{
    float u = 0.5f * (1.f + erf_fast((0.0f  - cdc) * inv_s));
    float v = 0.5f * (1.f + erf_fast((-0.1f - cdc) * inv_s));
    float w = 0.5f * (1.f + erf_fast((0.1f  - cdc) * inv_s));
    float inv = 1.f / fmaxf(w - v, 1e-10f);
    float pi0 = fminf(fmaxf((u - v) * inv, 0.f), 1.f);
    float pi1 = fminf(fmaxf((w - u) * inv, 0.f), 1.f);

    u = 0.5f * (1.f + erf_fast((0.0f  - cdn) * inv_s));
    v = 0.5f * (1.f + erf_fast((-0.1f - cdn) * inv_s));
    w = 0.5f * (1.f + erf_fast((0.1f  - cdn) * inv_s));
    inv = 1.f / fmaxf(w - v, 1e-10f);
    float pi0n = fminf(fmaxf((u - v) * inv, 0.f), 1.f);
    float pi1n = fminf(fmaxf((w - u) * inv, 0.f), 1.f);

    float rs = r0 * a0 + r1 * a1;
    float r  = (a0 >= a1) ? rs : 1.f - rs;      // argmax tie -> index 0
    float q0 = pi1 * r + pi0 * (1.f - r);
    float q1 = (2.f * r - 1.f) * (pi0 - pi1);
    if (!((a0 + a1) > 0.f)) { q0 = 1.f; q1 = 0.f; }
    return make_float4(q0, q1, beta * pi1n, beta * pi0n);
}

// be' = max(be*u, 1e-30) with u = q0+q1*p. Since q0,q1 come from convex
// combinations of [0,1]-clamped probabilities, u <= 1 (mod 2 ulp), so the
// floor max-scan collapses: over any chunk, be_out = max(be_in * U, 1e-30)
// with U = prod(u). Only U needs storing; the 2-ulp creep compounds to
// <= 1.0005x at the 1e-30 floor — invisible at the 2.9e-2 threshold.

// ---------------- Phase Aq: fused coeff-compute + per-chunk U ---------------
// Lane mapping: g = lane&7 (batch within octet), sl = lane>>3 (step/slot).
// Consecutive lanes -> consecutive b (record loads stride 44 B; QC stores
// 128 B contiguous per sl-group). Per 8-step block, lane (sl,g) computes
// record (t0+tt+sl, b_g); q is exchanged through LDS (wave-synchronous,
// broadcast reads, no barrier). Lane owns 7 slot-pairs {sl+16k, sl+16k+8}.
__global__ __launch_bounds__(256) void phaseAq_kernel(
    const float* __restrict__ x, const float* __restrict__ beta_raw,
    const float* __restrict__ sigma_raw, float4* __restrict__ QC,
    float* __restrict__ UC)
{
    __shared__ float2 sq[4][64];                 // per-wave q exchange (2 KB)
    const int lane = threadIdx.x & 63;
    const int wib  = threadIdx.x >> 6;
    const int W    = blockIdx.x * 4 + wib;       // 0..8191
    const int wg   = W & 255;                    // b-octet
    const int c    = W >> 8;                     // chunk 0..31
    const int g    = lane & 7;
    const int sl   = lane >> 3;
    const int b    = wg * 8 + g;
    const int t0   = c * LCH;
    float2* sqw = sq[wib];

    // per-b participant params (8 sl-lanes of a b redundant; coalesced reads)
    int pid = (int)nz(x[(size_t)b * FF + 10]);
    pid = pid < 0 ? 0 : (pid > PP - 1 ? PP - 1 : pid);
    float br = beta_raw[pid];
    float sr = sigma_raw[pid];
    float sp   = fmaxf(br, 0.f) + log1pf(__expf(-fabsf(br)));
    float beta = fminf(fmaxf(sp + 1.f, 1.f), 25.f);
    float sig  = fminf(fmaxf(__builtin_amdgcn_rcpf(1.f + __expf(-sr)) * 0.09f + 0.01f,
                             0.01f), 0.1f);
    float inv_s = 1.f / (sig * 1.41421356237309505f);

    f32x2 p[7];
    #pragma unroll
    for (int k = 0; k < 7; ++k)
        p[k] = (f32x2){ (float)(sl + 16 * k)     * (1.f / 99.f),
                        (float)(sl + 16 * k + 8) * (1.f / 99.f) };

    f32x2 U[7];
    #pragma unroll
    for (int k = 0; k < 7; ++k) U[k] = (f32x2){1.f, 1.f};

    // first record for this lane: t = t0 + sl
    const float* rp = x + ((size_t)(t0 + sl) * BB + b) * FF;
    float4 qc;
    {
        float a0 = nz(rp[0]), a1 = nz(rp[1]), r0 = nz(rp[2]),
              r1 = nz(rp[3]), dc = nz(rp[4]), dn = nz(rp[5]);
        qc = q_from_rec(a0, a1, r0, r1, dc, dn, beta, inv_s);
        QC[(size_t)(t0 + sl) * BB + b] = qc;
    }

    for (int tt = 0; tt < LCH; tt += 8) {
        const bool have = (tt + 8) < LCH;
        float na0, na1, nr0, nr1, ndc, ndn;
        if (have) {   // uniform branch; prefetch next block's record
            const float* np = x + ((size_t)(t0 + tt + 8 + sl) * BB + b) * FF;
            na0 = nz(np[0]); na1 = nz(np[1]); nr0 = nz(np[2]);
            nr1 = nz(np[3]); ndc = nz(np[4]); ndn = nz(np[5]);
        }
        // wave-synchronous q exchange: write own, broadcast-read per step
        sqw[sl * 8 + g] = make_float2(qc.x, qc.y);
        __builtin_amdgcn_wave_barrier();
        #pragma unroll
        for (int j = 0; j < 8; ++j) {
            float2 qj = sqw[j * 8 + g];          // 8 addrs, broadcast: no conflicts
            f32x2 qx = { qj.x, qj.x }, qy = { qj.y, qj.y };
            #pragma unroll
            for (int k = 0; k < 7; ++k) {
                f32x2 u = qy * p[k] + qx;        // v_pk_fma_f32
                U[k] *= u;                       // v_pk_mul_f32
            }
        }
        __builtin_amdgcn_wave_barrier();         // reads before next overwrite
        if (have) {   // compute + store next block's record
            qc = q_from_rec(na0, na1, nr0, nr1, ndc, ndn, beta, inv_s);
            QC[(size_t)(t0 + tt + 8 + sl) * BB + b] = qc;
        }
    }

    // UC layout [c][i][b]: consecutive lanes (b) -> coalesced float stores
    float* dst = UC + (size_t)c * (NG * BB) + b;
    #pragma unroll
    for (int k = 0; k < 6; ++k) {
        dst[(size_t)(sl + 16 * k) * BB]     = U[k].x;
        dst[(size_t)(sl + 16 * k + 8) * BB] = U[k].y;
    }
    if (sl < 4) dst[(size_t)(sl + 96) * BB] = U[6].x;
}

// ---------------- Phase B: 32-step scan over chunks per (i,b) ----------------
// flat = i*BB + b (layout [c][i][b]); elementwise over flat, coalesced.
__global__ __launch_bounds__(256) void phaseB_kernel(
    const float* __restrict__ UC, float* __restrict__ BE)
{
    const int flat = blockIdx.x * 256 + threadIdx.x;
    float be = 1.f;
    #pragma unroll
    for (int c = 0; c < NCH; ++c) {
        BE[(size_t)c * (BB * NG) + flat] = be;
        float u = UC[(size_t)c * (BB * NG) + flat];
        be = fmaxf(be * u, 1e-30f);              // constant-floor composition
    }
}

// ---------------- Phase C: parallel chunk re-walk, logits + carry ------------
// 8 lanes per b (sl = lane&7 -> contiguous groups, DPP-friendly), 8 b per wave.
__global__ __launch_bounds__(256) void phaseC_kernel(
    const float4* __restrict__ QC, const float* __restrict__ BE,
    float* __restrict__ out)
{
    const int lane = threadIdx.x & 63;
    const int wib  = threadIdx.x >> 6;
    const int W    = blockIdx.x * 4 + wib;       // 0..8191
    const int wg   = W & 255;                    // b-octet
    const int c    = W >> 8;                     // chunk 0..31
    const int sl   = lane & 7;
    const int g    = lane >> 3;
    const int b    = wg * 8 + g;
    const int t0   = c * LCH;

    f32x2 p[7];
    #pragma unroll
    for (int k = 0; k < 7; ++k)
        p[k] = (f32x2){ (float)(sl + 16 * k)     * (1.f / 99.f),
                        (float)(sl + 16 * k + 8) * (1.f / 99.f) };
    const f32x2 clA = { 1e-30f, 1e-30f };
    const f32x2 cl6 = { (sl < 4) ? 1e-30f : 0.f, 0.f };   // pair 6: i=96..111

    // chunk-entry beliefs from BE[c][i][b] (13 scattered loads, once per wave)
    const float* ebase = BE + (size_t)c * (BB * NG) + b;
    f32x2 be[7];
    #pragma unroll
    for (int k = 0; k < 6; ++k)
        be[k] = (f32x2){ ebase[(size_t)(sl + 16 * k) * BB],
                         ebase[(size_t)(sl + 16 * k + 8) * BB] };
    be[6] = (f32x2){ (sl < 4) ? ebase[(size_t)(sl + 96) * BB] : 0.f, 0.f };

    const char* QCb = (const char*)QC;
    char* outb = (char*)out;
    unsigned off  = ((unsigned)t0 * BB + (unsigned)b) * 16u;          // QC bytes
    unsigned soff = ((unsigned)t0 * (2 * BB) + 2 * (unsigned)b) * 4u; // out bytes

    float4 pre[JJ];
    #pragma unroll
    for (int j = 0; j < JJ; ++j)
        pre[j] = *(const float4*)(QCb + (off + (unsigned)j * (BB * 16u)));
    off += JJ * (BB * 16u);

    for (int tt = 0; tt < LCH; tt += JJ) {
        float S[JJ], Sp[JJ], Zv[JJ], Wv[JJ];
        #pragma unroll
        for (int j = 0; j < JJ; ++j) {
            float4 q = pre[j];
            // overrun prefetch (last iter, c=31) lands in UC region: never used
            pre[j] = *(const float4*)(QCb + (off + (unsigned)j * (BB * 16u)));
            f32x2 qx = { q.x, q.x }, qy = { q.y, q.y };
            #pragma unroll
            for (int k = 0; k < 7; ++k) {
                f32x2 u = qy * p[k] + qx;
                be[k] = __builtin_elementwise_max(be[k] * u,
                                                  (k == 6) ? cl6 : clA);
            }
            f32x2 sA = ((be[0] + be[1]) + (be[2] + be[3]))
                     + ((be[4] + be[5]) + be[6]);
            S[j] = sA.x + sA.y;
            f32x2 a1 = be[0] * p[0], a2 = be[1] * p[1];
            a1 = be[2] * p[2] + a1;  a2 = be[3] * p[3] + a2;
            a1 = be[4] * p[4] + a1;  a2 = be[5] * p[5] + a2;
            a1 = be[6] * p[6] + a1;
            f32x2 aa = a1 + a2;
            Sp[j] = aa.x + aa.y;
            Zv[j] = q.z;
            Wv[j] = q.w;
        }
        off += JJ * (BB * 16u);
        #pragma unroll
        for (int j = 0; j < JJ; ++j) {
            // 8-lane butterfly sum (pure VALU DPP)
            float st = S[j], sr = Sp[j];
            {
                int t;
                t = __builtin_amdgcn_update_dpp(0, __float_as_int(st), 0xB1, 0xF, 0xF, true);
                st += __int_as_float(t);
                t = __builtin_amdgcn_update_dpp(0, __float_as_int(sr), 0xB1, 0xF, 0xF, true);
                sr += __int_as_float(t);
                t = __builtin_amdgcn_update_dpp(0, __float_as_int(st), 0x4E, 0xF, 0xF, true);
                st += __int_as_float(t);
                t = __builtin_amdgcn_update_dpp(0, __float_as_int(sr), 0x4E, 0xF, 0xF, true);
                sr += __int_as_float(t);
                t = __builtin_amdgcn_update_dpp(0, __float_as_int(st), 0x141, 0xF, 0xF, true);
                st += __int_as_float(t);
                t = __builtin_amdgcn_update_dpp(0, __float_as_int(sr), 0x141, 0xF, 0xF, true);
                sr += __int_as_float(t);
            }
            float E  = sr * __builtin_amdgcn_rcpf(st);
            float A  = Wv[j] - Zv[j];
            float l0 = fmaf(A, E, Zv[j]);
            float l1 = fmaf(-A, E, Wv[j]);
            if (sl == 0)   // 8 lanes store 8B each; octet is 64B contiguous
                *(float2*)(outb + (soff + (unsigned)j * (2 * BB * 4u))) =
                    make_float2(l0, l1);
        }
        soff += JJ * (2 * BB * 4u);
    }

    if (c == NCH - 1) {   // final belief carry: out[T*B*2 + b*100 + i]
        float* bel = out + (size_t)TT * BB * 2 + (size_t)b * NG;
        #pragma unroll
        for (int k = 0; k < 6; ++k) {
            bel[sl + 16 * k]     = be[k].x;
            bel[sl + 16 * k + 8] = be[k].y;
        }
        if (sl < 4) bel[sl + 96] = be[6].x;
    }
}

extern "C" void kernel_launch(void* const* d_in, const int* in_sizes, int n_in,
                              void* d_out, int out_size, void* d_ws, size_t ws_size,
                              hipStream_t stream)
{
    const float* x         = (const float*)d_in[0];
    const float* beta_raw  = (const float*)d_in[1];
    const float* sigma_raw = (const float*)d_in[2];
    float* out = (float*)d_out;

    // workspace: QC (32 MiB) | UC (26.2 MB) | BE (26.2 MB)  ~= 85 MB
    char* ws = (char*)d_ws;
    float4* QC = (float4*)ws;
    float*  UC = (float*)(ws + (size_t)TT * BB * 16);
    float*  BE = (float*)(ws + (size_t)TT * BB * 16 + (size_t)NCH * BB * NG * 4);

    phaseAq_kernel<<<(BB / 8) * NCH / 4, 256, 0, stream>>>(x, beta_raw, sigma_raw, QC, UC);
    phaseB_kernel<<<(BB * NG) / 256, 256, 0, stream>>>(UC, BE);
    phaseC_kernel<<<(BB / 8) * NCH / 4, 256, 0, stream>>>(QC, BE, out);
}

// Round 12
// 192.486 us; speedup vs baseline: 1.0465x; 1.0189x over previous
//
#include <hip/hip_runtime.h>
#include <math.h>

#define TT  1024
#define BB  2048
#define FF  11
#define PP  256
#define NG  100
#define NCH 32           // chunks over T
#define LCH (TT / NCH)   // 32 steps per chunk
#define JJ  4            // phaseC unroll / prefetch depth

typedef float f32x2 __attribute__((ext_vector_type(2)));

__device__ __forceinline__ float nz(float v) { return (v != v) ? 0.f : v; }

// Branch-free erf, Abramowitz-Stegun 7.1.26, |err| <= 1.5e-7 (abs).
__device__ __forceinline__ float erf_fast(float x) {
    float ax = fabsf(x);
    float t  = __builtin_amdgcn_rcpf(fmaf(0.3275911f, ax, 1.f));
    float y  = fmaf(fmaf(fmaf(fmaf(1.061405429f, t, -1.453152027f), t,
                              1.421413741f), t, -0.284496736f), t, 0.254829592f);
    y *= t;
    float r = fmaf(-y, __expf(-ax * ax), 1.f);
    return copysignf(r, x);
}

// q coefficients for one (t,b) record. Returns (q0, q1, B0=beta*pi1n, B1=beta*pi0n).
__device__ __forceinline__ float4 q_from_rec(
    float a0, float a1, float r0, float r1, float cdc, float cdn,
    float beta, float inv_s)
{
    float u = 0.5f * (1.f + erf_fast((0.0f  - cdc) * inv_s));
    float v = 0.5f * (1.f + erf_fast((-0.1f - cdc) * inv_s));
    float w = 0.5f * (1.f + erf_fast((0.1f  - cdc) * inv_s));
    float inv = 1.f / fmaxf(w - v, 1e-10f);
    float pi0 = fminf(fmaxf((u - v) * inv, 0.f), 1.f);
    float pi1 = fminf(fmaxf((w - u) * inv, 0.f), 1.f);

    u = 0.5f * (1.f + erf_fast((0.0f  - cdn) * inv_s));
    v = 0.5f * (1.f + erf_fast((-0.1f - cdn) * inv_s));
    w = 0.5f * (1.f + erf_fast((0.1f  - cdn) * inv_s));
    inv = 1.f / fmaxf(w - v, 1e-10f);
    float pi0n = fminf(fmaxf((u - v) * inv, 0.f), 1.f);
    float pi1n = fminf(fmaxf((w - u) * inv, 0.f), 1.f);

    float rs = r0 * a0 + r1 * a1;
    float r  = (a0 >= a1) ? rs : 1.f - rs;      // argmax tie -> index 0
    float q0 = pi1 * r + pi0 * (1.f - r);
    float q1 = (2.f * r - 1.f) * (pi0 - pi1);
    if (!((a0 + a1) > 0.f)) { q0 = 1.f; q1 = 0.f; }
    return make_float4(q0, q1, beta * pi1n, beta * pi0n);
}

// be' = max(be*u, 1e-30) with u = q0+q1*p <= 1 (convex combo of clamped
// probs, mod 2 ulp): over a chunk, be_out = max(be_in * prod(u), 1e-30).
// Only U = prod(u) needs storing (validated R11: absmax unchanged).

// ---------------- Phase Aq: LDS-staged coeff-compute + per-chunk U ----------
// Wave W: b-octet wg = W & 255, chunk c = W >> 8. Lane (g = lane&7 = batch,
// sl = lane>>3 = step-in-block). The wave's whole x-slab (32 t x 8 b x 11 f
// = 11 KB) is staged into LDS with 11 coalesced float4 loads/lane (deep MLP),
// then the record reads / q-compute / exchange run entirely out of LDS.
// Lane owns 7 slot-pairs {sl+16k, sl+16k+8}; grid points >=100 are zeros.
__global__ __launch_bounds__(256) void phaseAq_kernel(
    const float* __restrict__ x, const float* __restrict__ beta_raw,
    const float* __restrict__ sigma_raw, float4* __restrict__ QC,
    float* __restrict__ UC)
{
    __shared__ float  sx[4][LCH * 88];           // 45056 B: x slab per wave
    __shared__ float2 sq[4][64];                 // 2048 B: q exchange per wave
    const int lane = threadIdx.x & 63;
    const int wib  = threadIdx.x >> 6;
    const int W    = blockIdx.x * 4 + wib;       // 0..8191
    const int wg   = W & 255;                    // b-octet
    const int c    = W >> 8;                     // chunk 0..31
    const int g    = lane & 7;
    const int sl   = lane >> 3;
    const int b    = wg * 8 + g;
    const int t0   = c * LCH;
    float*  sxw = sx[wib];
    float2* sqw = sq[wib];

    // ---- stage chunk x-slab: 32 rows x 88 floats = 704 float4, coalesced ----
    {
        const float4* x4 = (const float4*)x;     // row t: base (t*BB*FF)/4 = t*5632
        float4* s4 = (float4*)sxw;
        #pragma unroll
        for (int j = 0; j < 11; ++j) {
            int idx = lane + 64 * j;             // 0..703
            int row = idx / 22;                  // const-div -> magic mul
            int col = idx - row * 22;
            s4[idx] = x4[(size_t)(t0 + row) * 5632 + wg * 22 + col];
        }
    }

    // per-b participant params (overlaps staging loads; 8x redundant, cheap)
    int pid = (int)nz(x[(size_t)b * FF + 10]);
    pid = pid < 0 ? 0 : (pid > PP - 1 ? PP - 1 : pid);
    float br = beta_raw[pid];
    float sr = sigma_raw[pid];
    float sp   = fmaxf(br, 0.f) + log1pf(__expf(-fabsf(br)));
    float beta = fminf(fmaxf(sp + 1.f, 1.f), 25.f);
    float sig  = fminf(fmaxf(__builtin_amdgcn_rcpf(1.f + __expf(-sr)) * 0.09f + 0.01f,
                             0.01f), 0.1f);
    float inv_s = 1.f / (sig * 1.41421356237309505f);

    f32x2 p[7];
    #pragma unroll
    for (int k = 0; k < 7; ++k)
        p[k] = (f32x2){ (float)(sl + 16 * k)     * (1.f / 99.f),
                        (float)(sl + 16 * k + 8) * (1.f / 99.f) };

    f32x2 U[7];
    #pragma unroll
    for (int k = 0; k < 7; ++k) U[k] = (f32x2){1.f, 1.f};

    __syncthreads();                             // staging visible to all lanes

    for (int tt = 0; tt < LCH; tt += 8) {
        // own record from LDS: row tt+sl, record g (2-way bank alias = free)
        const float* rec = sxw + (tt + sl) * 88 + g * 11;
        float a0 = nz(rec[0]), a1 = nz(rec[1]), r0 = nz(rec[2]),
              r1 = nz(rec[3]), dc = nz(rec[4]), dn = nz(rec[5]);
        float4 qc = q_from_rec(a0, a1, r0, r1, dc, dn, beta, inv_s);
        QC[(size_t)(t0 + tt + sl) * BB + b] = qc;    // 128B contig per sl-group

        // wave-synchronous q exchange (pattern validated R11)
        sqw[sl * 8 + g] = make_float2(qc.x, qc.y);
        __builtin_amdgcn_wave_barrier();
        #pragma unroll
        for (int j = 0; j < 8; ++j) {
            float2 qj = sqw[j * 8 + g];          // 8 addrs, broadcast reads
            f32x2 qx = { qj.x, qj.x }, qy = { qj.y, qj.y };
            #pragma unroll
            for (int k = 0; k < 7; ++k) {
                f32x2 u = qy * p[k] + qx;        // v_pk_fma_f32
                U[k] *= u;                       // v_pk_mul_f32
            }
        }
        __builtin_amdgcn_wave_barrier();         // reads before next overwrite
    }

    // UC layout [c][i][b]: consecutive lanes (b) -> coalesced float stores
    float* dst = UC + (size_t)c * (NG * BB) + b;
    #pragma unroll
    for (int k = 0; k < 6; ++k) {
        dst[(size_t)(sl + 16 * k) * BB]     = U[k].x;
        dst[(size_t)(sl + 16 * k + 8) * BB] = U[k].y;
    }
    if (sl < 4) dst[(size_t)(sl + 96) * BB] = U[6].x;
}

// ---------------- Phase B: 32-step scan over chunks per (i,b) ----------------
// flat = i*BB + b (layout [c][i][b]); elementwise over flat, coalesced.
__global__ __launch_bounds__(256) void phaseB_kernel(
    const float* __restrict__ UC, float* __restrict__ BE)
{
    const int flat = blockIdx.x * 256 + threadIdx.x;
    float be = 1.f;
    #pragma unroll
    for (int c = 0; c < NCH; ++c) {
        BE[(size_t)c * (BB * NG) + flat] = be;
        float u = UC[(size_t)c * (BB * NG) + flat];
        be = fmaxf(be * u, 1e-30f);              // constant-floor composition
    }
}

// ---------------- Phase C: parallel chunk re-walk, logits + carry ------------
// 8 lanes per b (sl = lane&7 -> contiguous groups, DPP-friendly), 8 b per wave.
__global__ __launch_bounds__(256) void phaseC_kernel(
    const float4* __restrict__ QC, const float* __restrict__ BE,
    float* __restrict__ out)
{
    const int lane = threadIdx.x & 63;
    const int wib  = threadIdx.x >> 6;
    const int W    = blockIdx.x * 4 + wib;       // 0..8191
    const int wg   = W & 255;                    // b-octet
    const int c    = W >> 8;                     // chunk 0..31
    const int sl   = lane & 7;
    const int g    = lane >> 3;
    const int b    = wg * 8 + g;
    const int t0   = c * LCH;

    f32x2 p[7];
    #pragma unroll
    for (int k = 0; k < 7; ++k)
        p[k] = (f32x2){ (float)(sl + 16 * k)     * (1.f / 99.f),
                        (float)(sl + 16 * k + 8) * (1.f / 99.f) };
    const f32x2 clA = { 1e-30f, 1e-30f };
    const f32x2 cl6 = { (sl < 4) ? 1e-30f : 0.f, 0.f };   // pair 6: i=96..111

    // chunk-entry beliefs from BE[c][i][b] (13 scattered loads, once per wave)
    const float* ebase = BE + (size_t)c * (BB * NG) + b;
    f32x2 be[7];
    #pragma unroll
    for (int k = 0; k < 6; ++k)
        be[k] = (f32x2){ ebase[(size_t)(sl + 16 * k) * BB],
                         ebase[(size_t)(sl + 16 * k + 8) * BB] };
    be[6] = (f32x2){ (sl < 4) ? ebase[(size_t)(sl + 96) * BB] : 0.f, 0.f };

    const char* QCb = (const char*)QC;
    char* outb = (char*)out;
    unsigned off  = ((unsigned)t0 * BB + (unsigned)b) * 16u;          // QC bytes
    unsigned soff = ((unsigned)t0 * (2 * BB) + 2 * (unsigned)b) * 4u; // out bytes

    float4 pre[JJ];
    #pragma unroll
    for (int j = 0; j < JJ; ++j)
        pre[j] = *(const float4*)(QCb + (off + (unsigned)j * (BB * 16u)));
    off += JJ * (BB * 16u);

    for (int tt = 0; tt < LCH; tt += JJ) {
        float S[JJ], Sp[JJ], Zv[JJ], Wv[JJ];
        #pragma unroll
        for (int j = 0; j < JJ; ++j) {
            float4 q = pre[j];
            // overrun prefetch (last iter, c=31) lands in UC region: never used
            pre[j] = *(const float4*)(QCb + (off + (unsigned)j * (BB * 16u)));
            f32x2 qx = { q.x, q.x }, qy = { q.y, q.y };
            #pragma unroll
            for (int k = 0; k < 7; ++k) {
                f32x2 u = qy * p[k] + qx;
                be[k] = __builtin_elementwise_max(be[k] * u,
                                                  (k == 6) ? cl6 : clA);
            }
            f32x2 sA = ((be[0] + be[1]) + (be[2] + be[3]))
                     + ((be[4] + be[5]) + be[6]);
            S[j] = sA.x + sA.y;
            f32x2 a1 = be[0] * p[0], a2 = be[1] * p[1];
            a1 = be[2] * p[2] + a1;  a2 = be[3] * p[3] + a2;
            a1 = be[4] * p[4] + a1;  a2 = be[5] * p[5] + a2;
            a1 = be[6] * p[6] + a1;
            f32x2 aa = a1 + a2;
            Sp[j] = aa.x + aa.y;
            Zv[j] = q.z;
            Wv[j] = q.w;
        }
        off += JJ * (BB * 16u);
        #pragma unroll
        for (int j = 0; j < JJ; ++j) {
            // 8-lane butterfly sum (pure VALU DPP)
            float st = S[j], sr = Sp[j];
            {
                int t;
                t = __builtin_amdgcn_update_dpp(0, __float_as_int(st), 0xB1, 0xF, 0xF, true);
                st += __int_as_float(t);
                t = __builtin_amdgcn_update_dpp(0, __float_as_int(sr), 0xB1, 0xF, 0xF, true);
                sr += __int_as_float(t);
                t = __builtin_amdgcn_update_dpp(0, __float_as_int(st), 0x4E, 0xF, 0xF, true);
                st += __int_as_float(t);
                t = __builtin_amdgcn_update_dpp(0, __float_as_int(sr), 0x4E, 0xF, 0xF, true);
                sr += __int_as_float(t);
                t = __builtin_amdgcn_update_dpp(0, __float_as_int(st), 0x141, 0xF, 0xF, true);
                st += __int_as_float(t);
                t = __builtin_amdgcn_update_dpp(0, __float_as_int(sr), 0x141, 0xF, 0xF, true);
                sr += __int_as_float(t);
            }
            float E  = sr * __builtin_amdgcn_rcpf(st);
            float A  = Wv[j] - Zv[j];
            float l0 = fmaf(A, E, Zv[j]);
            float l1 = fmaf(-A, E, Wv[j]);
            if (sl == 0)   // 8 lanes store 8B each; octet is 64B contiguous
                *(float2*)(outb + (soff + (unsigned)j * (2 * BB * 4u))) =
                    make_float2(l0, l1);
        }
        soff += JJ * (2 * BB * 4u);
    }

    if (c == NCH - 1) {   // final belief carry: out[T*B*2 + b*100 + i]
        float* bel = out + (size_t)TT * BB * 2 + (size_t)b * NG;
        #pragma unroll
        for (int k = 0; k < 6; ++k) {
            bel[sl + 16 * k]     = be[k].x;
            bel[sl + 16 * k + 8] = be[k].y;
        }
        if (sl < 4) bel[sl + 96] = be[6].x;
    }
}

extern "C" void kernel_launch(void* const* d_in, const int* in_sizes, int n_in,
                              void* d_out, int out_size, void* d_ws, size_t ws_size,
                              hipStream_t stream)
{
    const float* x         = (const float*)d_in[0];
    const float* beta_raw  = (const float*)d_in[1];
    const float* sigma_raw = (const float*)d_in[2];
    float* out = (float*)d_out;

    // workspace: QC (32 MiB) | UC (26.2 MB) | BE (26.2 MB)  ~= 85 MB
    char* ws = (char*)d_ws;
    float4* QC = (float4*)ws;
    float*  UC = (float*)(ws + (size_t)TT * BB * 16);
    float*  BE = (float*)(ws + (size_t)TT * BB * 16 + (size_t)NCH * BB * NG * 4);

    phaseAq_kernel<<<(BB / 8) * NCH / 4, 256, 0, stream>>>(x, beta_raw, sigma_raw, QC, UC);
    phaseB_kernel<<<(BB * NG) / 256, 256, 0, stream>>>(UC, BE);
    phaseC_kernel<<<(BB / 8) * NCH / 4, 256, 0, stream>>>(QC, BE, out);
}